// Round 9
// baseline (369.812 us; speedup 1.0000x reference)
//
#include <hip/hip_runtime.h>
#include <math.h>

typedef _Float16 f16x8 __attribute__((ext_vector_type(8)));
typedef float    f32x4 __attribute__((ext_vector_type(4)));

constexpr int kT     = 512;   // sequence length
constexpr int kH     = 16;    // hidden
constexpr int kL     = 8;     // layers
constexpr int kNB    = 4;     // batches per block -> 512 blocks = 2 per CU
constexpr int kSlots = 8;     // ring depth (slot = t & 7)
constexpr int kLyr   = kL + 1;            // region 0 = x, region l+1 = layer l h
constexpr int kRows  = 5;     // 4 batch rows + permanent zero row
constexpr int kRowE  = 16;    // f16 per row (32 B)
constexpr int kSE    = kLyr * kRows * kRowE;   // 720 f16 = 1440 B per slot
constexpr int kEp    = 263;   // epochs of 2 timesteps; layer7 t=511 at ep 262

constexpr float kL2E = 1.4426950408889634f;

__device__ __forceinline__ float ex2(float w)  { return __builtin_amdgcn_exp2f(w); }
__device__ __forceinline__ float rcpf(float e) { return __builtin_amdgcn_rcpf(e); }

// Round-18: 2 timesteps per barrier epoch, all-register recurrence hops.
//  - walls 528 -> 263: the ~960cy {barrier+chain} unit proved invariant
//    (R1-R7 elimination series), so halve how many we pay.
//  - step A: B2 = bperm results carried across the barrier in registers
//  - step B: B2 = step A's h, pair-packed via shfl_xor(16) then gathered
//    with 4 ds_bpermute (owner lane of unit v = 16*(v&3)+bl+4*((v>>2)&1)
//    +8*(v>>3); every lane owns exactly one (unit,batch) cell - R16 map)
//  - !bact lanes mask their gathered fragment to 0 (zero-row semantics)
//  - LDS: only cross-layer B1 (2x b128 read) + h/x publishes per epoch;
//    write-completion proven by the shfl_B data-wait (in-order DS), final
//    drain lgkmcnt(4) leaves next epoch's 4 bpermutes in flight
//  - grid/map/activation/head verbatim from verified R16 (absmax 0)
__global__ __launch_bounds__(512, 4)
void lstm_bp2(const float* __restrict__ x,
              const float* __restrict__ Wih, const float* __restrict__ Whh,
              const float* __restrict__ bih, const float* __restrict__ bhh,
              const float* __restrict__ Wp,  const float* __restrict__ bpos,
              const float* __restrict__ Wo,  const float* __restrict__ bori,
              float* __restrict__ out)
{
    const int tid  = threadIdx.x;
    const int l    = tid >> 6;        // wave = layer
    const int lane = tid & 63;
    const int n    = lane & 15;
    const int q    = lane >> 4;
    const int bl   = n & 3;           // batch within block
    const int g2   = (n >> 2) & 1;    // diag-block selector
    const int hi   = n >> 3;          // own-tile select bit
    const bool bact = ((q >> 1) == g2);

    __shared__ __align__(16) _Float16 hb[kSlots][kLyr][kRows][kRowE]; // 11520 B

    {   // zero-init LDS
        int* hz = (int*)&hb[0][0][0][0];
        for (int i = tid; i < (int)(sizeof(hb) / 4); i += 512) hz[i] = 0;
    }
    __syncthreads();

    // ---- A fragments (both tiles) + scaled bias C-init (R16 verbatim) ----
    const float asc = ((n & 3) == 2) ? (-2.0f * kL2E) : (-kL2E);
    auto loadA = [&](const float* W, int T) -> f16x8 {
        const int wrow = (n & 3) * 16 + (n >> 2) + 4 * (q >> 1) + 8 * T;
        const float* src = W + (size_t)l * 64 * kH + wrow * kH;
        f16x8 a;
        #pragma unroll
        for (int j = 0; j < 8; ++j)
            a[j] = (_Float16)(asc * src[(q & 1) * 8 + j]);
        return a;
    };
    const f16x8 A1T0 = loadA(Wih, 0), A1T1 = loadA(Wih, 1);
    const f16x8 A2T0 = loadA(Whh, 0), A2T1 = loadA(Whh, 1);

    const int u0b = q + 4 * g2;
    f32x4 biasT0, biasT1;
    #pragma unroll
    for (int r = 0; r < 4; ++r) {
        const float sc = (r == 2) ? (-2.0f * kL2E) : (-kL2E);
        const int g0 = l * 64 + r * 16 + u0b;
        biasT0[r] = sc * (bih[g0] + bhh[g0]);
        biasT1[r] = sc * (bih[g0 + 8] + bhh[g0 + 8]);
    }

    // ---- LDS pointers ----
    const int boff = (bact ? bl * kRowE : 4 * kRowE) + (q & 1) * 8;
    const _Float16* b1b = &hb[0][l][0][0] + boff;   // upstream h / x (B1)
    const int um = u0b + 8 * hi;                    // lane's own unit
    _Float16* hw = &hb[0][l + 1][bl][um];           // h publish (b16)
    _Float16* xw = &hb[0][0][bl][um];               // x publish (b16)

    // ---- bpermute addresses: dword d of B2 = units (v0, v0+1),
    //      v0 = (q&1)*8 + 2d; holder = even-q owner of v0 ----
    int bpa[4];
    #pragma unroll
    for (int d = 0; d < 4; ++d) {
        const int v0 = (q & 1) * 8 + 2 * d;
        const int Lh = 16 * (v0 & 3) + bl + 4 * ((v0 >> 2) & 1) + 8 * (v0 >> 3);
        bpa[d] = 4 * Lh;
    }
    const int msk = bact ? ~0 : 0;

    // ---- x staging (wave 0): slot t&7 holds x(t). Prime x(0..7);
    //      regs xr0..xr3 = x(8..11) (2-epoch load-to-use distance) ----
    const float* xg = x + ((size_t)(blockIdx.x * kNB + bl) * kT) * kH + um;
    float xr0 = 0.f, xr1 = 0.f, xr2 = 0.f, xr3 = 0.f;
    if (l == 0) {
        #pragma unroll
        for (int t = 0; t < 8; ++t)
            hb[t][0][bl][um] = (_Float16)xg[(size_t)t * kH];
        xr0 = xg[ 8 * (size_t)kH];
        xr1 = xg[ 9 * (size_t)kH];
        xr2 = xg[10 * (size_t)kH];
        xr3 = xg[11 * (size_t)kH];
    }
    __syncthreads();

    int nb0 = 0, nb1 = 0, nb2 = 0, nb3 = 0;   // carried bperm results (B2 of step A)
    float c0 = 0.f;
    int te   = -2 * l;                        // timestep of step A this epoch
    int offA = ((-2 * l) & 7) * kSE;          // slot te&7 (f16 elems)

    #pragma unroll 1
    for (int ep = 0; ep < kEp; ++ep) {
        const int offB = offA + kSE;          // slot te+1 (te even -> no wrap)
        const bool activeA = ((unsigned)te       < (unsigned)kT);
        const bool activeB = ((unsigned)(te + 1) < (unsigned)kT);

        // B1 for both steps (written by upstream last epoch, barrier-fenced)
        const f16x8 B1a = *(const f16x8*)(b1b + offA);
        const f16x8 B1b = *(const f16x8*)(b1b + offB);

        // B2 of step A: carried bperm results (compiler waits lgkm on use)
        union { int i[4]; f16x8 v; } uA;
        uA.i[0] = nb0 & msk; uA.i[1] = nb1 & msk;
        uA.i[2] = nb2 & msk; uA.i[3] = nb3 & msk;
        const f16x8 B2A = uA.v;

        // ---- step A ----
        f32x4 dIn0 = __builtin_amdgcn_mfma_f32_16x16x32_f16(A1T0, B1a, biasT0, 0, 0, 0);
        f32x4 dIn1 = __builtin_amdgcn_mfma_f32_16x16x32_f16(A1T1, B1a, biasT1, 0, 0, 0);
        f32x4 dT0  = __builtin_amdgcn_mfma_f32_16x16x32_f16(A2T0, B2A, dIn0, 0, 0, 0);
        f32x4 dT1  = __builtin_amdgcn_mfma_f32_16x16x32_f16(A2T1, B2A, dIn1, 0, 0, 0);
        f32x4 d;
        #pragma unroll
        for (int r = 0; r < 4; ++r) d[r] = hi ? dT1[r] : dT0[r];

        float hA;
        {   // 7-trans cell update (verified algebra + clamps)
            const float Ei = ex2(fminf(d[0], 40.0f));
            const float Ef = ex2(fminf(d[1], 40.0f));
            const float Eg = ex2(fminf(d[2], 40.0f));
            const float Eo = ex2(fminf(d[3], 60.0f));
            const float Dg = 1.0f + Eg;
            const float Df = 1.0f + Ef;
            const float P1  = fmaf(Ei, Dg, Dg);
            const float den = Df * P1;
            const float t2  = fmaf(-Eg, Df, Df);
            const float num = fmaf(c0, P1, t2);
            float cn = num * rcpf(den);
            cn = activeA ? cn : 0.0f;
            c0 = cn;
            const float ac = fminf(cn * (-2.0f * kL2E), 60.0f);
            const float Ec = ex2(ac);
            const float Do = 1.0f + Eo;
            const float R2 = rcpf(fmaf(Do, Ec, Do));
            hA = fmaf(-Ec, R2, R2);
        }

        // publish h(te); x(te+8) rides the same slot
        *(hw + offA) = (_Float16)hA;
        if (l == 0) *(xw + offA) = (_Float16)xr0;

        // pack pair (own unit, partner unit) and gather B2 of step B
        const unsigned oA = (unsigned)__builtin_bit_cast(unsigned short, (_Float16)hA);
        const unsigned pA = (unsigned)__shfl_xor((int)oA, 16, 64);
        const unsigned packedA = (q & 1) ? ((oA << 16) | pA) : ((pA << 16) | oA);
        union { int i[4]; f16x8 v; } uB;
        uB.i[0] = __builtin_amdgcn_ds_bpermute(bpa[0], (int)packedA) & msk;
        uB.i[1] = __builtin_amdgcn_ds_bpermute(bpa[1], (int)packedA) & msk;
        uB.i[2] = __builtin_amdgcn_ds_bpermute(bpa[2], (int)packedA) & msk;
        uB.i[3] = __builtin_amdgcn_ds_bpermute(bpa[3], (int)packedA) & msk;
        const f16x8 B2B = uB.v;

        // ---- step B ----
        dIn0 = __builtin_amdgcn_mfma_f32_16x16x32_f16(A1T0, B1b, biasT0, 0, 0, 0);
        dIn1 = __builtin_amdgcn_mfma_f32_16x16x32_f16(A1T1, B1b, biasT1, 0, 0, 0);
        dT0  = __builtin_amdgcn_mfma_f32_16x16x32_f16(A2T0, B2B, dIn0, 0, 0, 0);
        dT1  = __builtin_amdgcn_mfma_f32_16x16x32_f16(A2T1, B2B, dIn1, 0, 0, 0);
        #pragma unroll
        for (int r = 0; r < 4; ++r) d[r] = hi ? dT1[r] : dT0[r];

        float hB;
        {
            const float Ei = ex2(fminf(d[0], 40.0f));
            const float Ef = ex2(fminf(d[1], 40.0f));
            const float Eg = ex2(fminf(d[2], 40.0f));
            const float Eo = ex2(fminf(d[3], 60.0f));
            const float Dg = 1.0f + Eg;
            const float Df = 1.0f + Ef;
            const float P1  = fmaf(Ei, Dg, Dg);
            const float den = Df * P1;
            const float t2  = fmaf(-Eg, Df, Df);
            const float num = fmaf(c0, P1, t2);
            float cn = num * rcpf(den);
            cn = activeB ? cn : 0.0f;
            c0 = cn;
            const float ac = fminf(cn * (-2.0f * kL2E), 60.0f);
            const float Ec = ex2(ac);
            const float Do = 1.0f + Eo;
            const float R2 = rcpf(fmaf(Do, Ec, Do));
            hB = fmaf(-Ec, R2, R2);
        }

        // publish h(te+1); x(te+9); rotate x prefetch (2-epoch distance)
        *(hw + offB) = (_Float16)hB;
        if (l == 0) {
            *(xw + offB) = (_Float16)xr1;
            xr0 = xr2; xr1 = xr3;
            int t2i = te + 12; if (t2i > kT - 1) t2i = kT - 1;
            int t3i = te + 13; if (t3i > kT - 1) t3i = kT - 1;
            xr2 = xg[(size_t)t2i * kH];
            xr3 = xg[(size_t)t3i * kH];
        }

        // pin: all DS writes above stay above; bperms below stay below.
        __builtin_amdgcn_sched_barrier(0);

        // next epoch's B2A gather: issued pre-barrier, rides across in flight
        const unsigned oB = (unsigned)__builtin_bit_cast(unsigned short, (_Float16)hB);
        const unsigned pB = (unsigned)__shfl_xor((int)oB, 16, 64);
        const unsigned packedB = (q & 1) ? ((oB << 16) | pB) : ((pB << 16) | oB);
        nb0 = __builtin_amdgcn_ds_bpermute(bpa[0], (int)packedB);
        nb1 = __builtin_amdgcn_ds_bpermute(bpa[1], (int)packedB);
        nb2 = __builtin_amdgcn_ds_bpermute(bpa[2], (int)packedB);
        nb3 = __builtin_amdgcn_ds_bpermute(bpa[3], (int)packedB);
        __builtin_amdgcn_sched_barrier(0);

        te += 2;
        offA += 2 * kSE; if (offA >= 8 * kSE) offA -= 8 * kSE;

        // shfl_B's data-wait already proved the h/x writes complete (in-order
        // DS); leave the 4 bperms in flight across the barrier.
        asm volatile("s_waitcnt lgkmcnt(4)\n\ts_barrier" ::: "memory");
    }

    __syncthreads();

    // ---- head: layer-7 h(511) -> slot 511&7 = 7, region 8 (R16 verbatim) ----
    if (l == kL - 1 && lane < 32) {
        const int bb = lane >> 3;         // batch 0..3
        const int r  = lane & 7;
        if (r < 6) {
            const bool  isP   = (r < 3);
            const float* wrow = isP ? (Wp + r * kH) : (Wo + (r - 3) * kH);
            float acc = isP ? bpos[r] : bori[r - 3];
            #pragma unroll
            for (int u = 0; u < kH; ++u)
                acc = fmaf((float)hb[7][kL][bb][u], wrow[u], acc);
            if (!isP) {
                const float Et = ex2(-2.0f * kL2E * acc);
                acc = fmaf(2.0f, rcpf(1.0f + Et), -1.0f);
            }
            out[(size_t)(blockIdx.x * kNB + bb) * 6 + r] = acc;
        }
    }
}

extern "C" void kernel_launch(void* const* d_in, const int* in_sizes, int n_in,
                              void* d_out, int out_size, void* d_ws, size_t ws_size,
                              hipStream_t stream) {
    const float* x    = (const float*)d_in[0];
    const float* Wih  = (const float*)d_in[1];
    const float* Whh  = (const float*)d_in[2];
    const float* bih  = (const float*)d_in[3];
    const float* bhh  = (const float*)d_in[4];
    const float* Wp   = (const float*)d_in[5];
    const float* bpos = (const float*)d_in[6];
    const float* Wo   = (const float*)d_in[7];
    const float* bori = (const float*)d_in[8];
    float* out = (float*)d_out;

    const int B = in_sizes[0] / (kT * kH);   // 2048
    lstm_bp2<<<dim3(B / kNB), dim3(512), 0, stream>>>(x, Wih, Whh, bih, bhh,
                                                      Wp, bpos, Wo, bori, out);
}

// Round 11
// 308.237 us; speedup vs baseline: 1.1998x; 1.1998x over previous
//
#include <hip/hip_runtime.h>
#include <math.h>

typedef _Float16 f16x4 __attribute__((ext_vector_type(4)));
typedef _Float16 f16x2 __attribute__((ext_vector_type(2)));
typedef float    f32x4 __attribute__((ext_vector_type(4)));

constexpr int kT      = 512;   // sequence length
constexpr int kH      = 16;    // hidden
constexpr int kL      = 8;     // layers
constexpr int kNB     = 8;     // batches per block -> 256 blocks = 1/CU
constexpr int kC      = 16;    // chunk length (timesteps per stage)
constexpr int kChunks = kT / kC;            // 32
constexpr int kStages = kChunks + kL - 1;   // 39 barriers total
constexpr int kRowE   = kNB * kH;           // f16 per chunk-step row (128)

constexpr float kL2E = 1.4426950408889634f;

__device__ __forceinline__ float ex2(float w)  { return __builtin_amdgcn_exp2f(w); }
__device__ __forceinline__ float rcpf(float e) { return __builtin_amdgcn_rcpf(e); }

// Round-19b: chunked wavefront pipeline — sync every 16 steps, not every step.
// (Resubmission of R19: bench infra failed; audit found no kernel defect.)
//  - R1-R8 elimination series: every step-synchronous structure costs
//    ~960-1500 cy/step invariant to contents -> amortize the handoff.
//  - wave l owns layer l for the WHOLE sequence; recurrence state (c, h)
//    register-resident for all 512 steps (lstm_rr8 per-step structure,
//    harness-verified absmax 0: per-gate 16x16x16 MFMAs, D->B2 via one
//    shfl_xor(8), 2 cells/lane, 7-trans activation with clamps)
//  - stage s: wave l runs chunk c = s - l (16 steps, no internal sync);
//    h chunk published to double-buffered LDS ring (parity c&1); ONE
//    barrier per stage (39 total, was 528)
//  - B1 fragments for the whole chunk preloaded at stage top:
//    l>0: 16x ds_read_b64 from upstream chunk (written last stage);
//    l==0: register-prefetched x chunk (f32x4, loaded during prev stage,
//    vmcnt rides across barriers), converted to f16 at stage top
//  - layer 7 publishes nothing per chunk (no reader); writes h(511) to a
//    tiny head buffer at its last step
__global__ __launch_bounds__(512, 2)
void lstm_ck(const float* __restrict__ x,
             const float* __restrict__ Wih, const float* __restrict__ Whh,
             const float* __restrict__ bih, const float* __restrict__ bhh,
             const float* __restrict__ Wp,  const float* __restrict__ bpos,
             const float* __restrict__ Wo,  const float* __restrict__ bori,
             float* __restrict__ out)
{
    const int tid  = threadIdx.x;
    const int l    = tid >> 6;        // wave = layer (permanent)
    const int lane = tid & 63;
    const int n    = lane & 15;
    const int q    = lane >> 4;
    const int b    = n & 7;           // batch (MFMA cols duplicated n / n+8)
    const int hi   = n >> 3;          // which cell-pair this lane activates

    // double-buffered chunk ring for layers 0..6 (layer 7 has no reader)
    __shared__ __align__(16) _Float16 hbuf[2][kL - 1][kC][kNB][kH]; // 57344 B
    __shared__ __align__(16) _Float16 headb[kNB][kH];               // 256 B

    // ---- A fragments + scaled bias C-init (lstm_rr8 verbatim) ----
    // A_p row m=n -> W row (n&3)*16 + 4*(n>>2) + p, cols k = 4q..4q+3
    const float asc = ((n & 3) == 2) ? (-2.0f * kL2E) : (-kL2E);
    f16x4 A1[4], A2[4];
    f32x4 bias[4];
    #pragma unroll
    for (int p = 0; p < 4; ++p) {
        const int wrow = (n & 3) * 16 + 4 * (n >> 2) + p;
        const float* w1 = Wih + (size_t)l * 64 * kH + wrow * kH + 4 * q;
        const float* w2 = Whh + (size_t)l * 64 * kH + wrow * kH + 4 * q;
        #pragma unroll
        for (int jj = 0; jj < 4; ++jj) {
            A1[p][jj] = (_Float16)(asc * w1[jj]);
            A2[p][jj] = (_Float16)(asc * w2[jj]);
        }
        #pragma unroll
        for (int r = 0; r < 4; ++r) {   // C-init: gate r of unit 4q+p
            const float sc = (r == 2) ? (-2.0f * kL2E) : (-kL2E);
            const int g0 = l * 64 + r * 16 + 4 * q + p;
            bias[p][r] = sc * (bih[g0] + bhh[g0]);
        }
    }

    // ---- x prefetch registers (wave 0): chunk 0 primed here ----
    const float* xg = x + ((size_t)(blockIdx.x * kNB + b) * kT) * kH + 4 * q;
    f32x4 xf[kC];
    if (l == 0) {
        #pragma unroll
        for (int j = 0; j < kC; ++j)
            xf[j] = *(const f32x4*)(xg + (size_t)j * kH);
    }

    f16x4 B2r = { (_Float16)0.f, (_Float16)0.f, (_Float16)0.f, (_Float16)0.f };
    float cA = 0.f, cB = 0.f;     // register cell state, whole sequence

    #pragma unroll 1
    for (int s = 0; s < kStages; ++s) {
        const int c = s - l;                      // this wave's chunk index
        if ((unsigned)c < (unsigned)kChunks) {    // wave-uniform
            // ---- stage top: gather all 16 B1 fragments ----
            f16x4 B1f[kC];
            if (l == 0) {
                #pragma unroll
                for (int j = 0; j < kC; ++j) {
                    f16x4 v = { (_Float16)xf[j][0], (_Float16)xf[j][1],
                                (_Float16)xf[j][2], (_Float16)xf[j][3] };
                    B1f[j] = v;
                }
                if (c + 1 < kChunks) {            // prefetch next x chunk
                    #pragma unroll
                    for (int j = 0; j < kC; ++j)
                        xf[j] = *(const f32x4*)(xg + (size_t)((c + 1) * kC + j) * kH);
                }
            } else {
                const _Float16* src = &hbuf[c & 1][l - 1][0][b][4 * q];
                #pragma unroll
                for (int j = 0; j < kC; ++j)
                    B1f[j] = *(const f16x4*)(src + j * kRowE);
            }

            _Float16* wdst = &hbuf[c & 1][(l < kL - 1) ? l : 0][0][b][4 * q + 2 * hi];

            // ---- 16 register-resident steps, no sync ----
            #pragma unroll
            for (int j = 0; j < kC; ++j) {
                // input half (off-chain; compiler pipelines across steps)
                f32x4 dIn0 = __builtin_amdgcn_mfma_f32_16x16x16f16(A1[0], B1f[j], bias[0], 0, 0, 0);
                f32x4 dIn1 = __builtin_amdgcn_mfma_f32_16x16x16f16(A1[1], B1f[j], bias[1], 0, 0, 0);
                f32x4 dIn2 = __builtin_amdgcn_mfma_f32_16x16x16f16(A1[2], B1f[j], bias[2], 0, 0, 0);
                f32x4 dIn3 = __builtin_amdgcn_mfma_f32_16x16x16f16(A1[3], B1f[j], bias[3], 0, 0, 0);
                // chain head: all operands in registers
                f32x4 d0 = __builtin_amdgcn_mfma_f32_16x16x16f16(A2[0], B2r, dIn0, 0, 0, 0);
                f32x4 d1 = __builtin_amdgcn_mfma_f32_16x16x16f16(A2[1], B2r, dIn1, 0, 0, 0);
                f32x4 d2 = __builtin_amdgcn_mfma_f32_16x16x16f16(A2[2], B2r, dIn2, 0, 0, 0);
                f32x4 d3 = __builtin_amdgcn_mfma_f32_16x16x16f16(A2[3], B2r, dIn3, 0, 0, 0);

                f32x4 dA, dB;
                #pragma unroll
                for (int r = 0; r < 4; ++r) {
                    dA[r] = hi ? d2[r] : d0[r];     // cell unit 4q + 2hi
                    dB[r] = hi ? d3[r] : d1[r];     // cell unit 4q + 2hi + 1
                }

                float hAf, hBf;
                {   // 7-trans cell update (verified algebra + clamps)
                    const float Ei = ex2(fminf(dA[0], 40.0f));
                    const float Ef = ex2(fminf(dA[1], 40.0f));
                    const float Eg = ex2(fminf(dA[2], 40.0f));
                    const float Eo = ex2(fminf(dA[3], 60.0f));
                    const float Dg = 1.0f + Eg;
                    const float Df = 1.0f + Ef;
                    const float P1  = fmaf(Ei, Dg, Dg);
                    const float den = Df * P1;
                    const float t2  = fmaf(-Eg, Df, Df);
                    const float num = fmaf(cA, P1, t2);
                    const float cn  = num * rcpf(den);
                    cA = cn;
                    const float ac = fminf(cn * (-2.0f * kL2E), 60.0f);
                    const float Ec = ex2(ac);
                    const float Do = 1.0f + Eo;
                    const float R2 = rcpf(fmaf(Do, Ec, Do));
                    hAf = fmaf(-Ec, R2, R2);
                }
                {
                    const float Ei = ex2(fminf(dB[0], 40.0f));
                    const float Ef = ex2(fminf(dB[1], 40.0f));
                    const float Eg = ex2(fminf(dB[2], 40.0f));
                    const float Eo = ex2(fminf(dB[3], 60.0f));
                    const float Dg = 1.0f + Eg;
                    const float Df = 1.0f + Ef;
                    const float P1  = fmaf(Ei, Dg, Dg);
                    const float den = Df * P1;
                    const float t2  = fmaf(-Eg, Df, Df);
                    const float num = fmaf(cB, P1, t2);
                    const float cn  = num * rcpf(den);
                    cB = cn;
                    const float ac = fminf(cn * (-2.0f * kL2E), 60.0f);
                    const float Ec = ex2(ac);
                    const float Do = 1.0f + Eo;
                    const float R2 = rcpf(fmaf(Do, Ec, Do));
                    hBf = fmaf(-Ec, R2, R2);
                }

                // pack own pair; partner pair via lane^8; assemble B2 (regs)
                f16x2 hp = { (_Float16)hAf, (_Float16)hBf };
                union { f16x2 h; int i; } uh; uh.h = hp;
                const int own   = uh.i;
                const int other = __shfl_xor(own, 8, 64);
                union { int i2[2]; f16x4 v; } ub;
                ub.i2[0] = hi ? other : own;    // units 4q, 4q+1
                ub.i2[1] = hi ? own : other;    // units 4q+2, 4q+3
                B2r = ub.v;

                // publish h(t) for downstream layer (off-chain)
                if (l < kL - 1)
                    *(f16x2*)(wdst + j * kRowE) = hp;
                if (l == kL - 1 && c == kChunks - 1 && j == kC - 1)
                    *(f16x2*)(&headb[b][4 * q + 2 * hi]) = hp;
            }
        }
        // end of stage: drain DS (chunk writes visible), one barrier.
        // vmcnt NOT drained: wave 0's x prefetch spans stages.
        asm volatile("s_waitcnt lgkmcnt(0)\n\ts_barrier" ::: "memory");
    }

    __syncthreads();

    // ---- head: layer-7 h(511) from headb ----
    if (l == kL - 1) {
        const int bb = lane >> 3;         // batch 0..7
        const int r  = lane & 7;
        if (r < 6) {
            const bool  isP   = (r < 3);
            const float* wrow = isP ? (Wp + r * kH) : (Wo + (r - 3) * kH);
            float acc = isP ? bpos[r] : bori[r - 3];
            #pragma unroll
            for (int u = 0; u < kH; ++u)
                acc = fmaf((float)headb[bb][u], wrow[u], acc);
            if (!isP) {
                const float Et = ex2(-2.0f * kL2E * acc);
                acc = fmaf(2.0f, rcpf(1.0f + Et), -1.0f);
            }
            out[(size_t)(blockIdx.x * kNB + bb) * 6 + r] = acc;
        }
    }
}

extern "C" void kernel_launch(void* const* d_in, const int* in_sizes, int n_in,
                              void* d_out, int out_size, void* d_ws, size_t ws_size,
                              hipStream_t stream) {
    const float* x    = (const float*)d_in[0];
    const float* Wih  = (const float*)d_in[1];
    const float* Whh  = (const float*)d_in[2];
    const float* bih  = (const float*)d_in[3];
    const float* bhh  = (const float*)d_in[4];
    const float* Wp   = (const float*)d_in[5];
    const float* bpos = (const float*)d_in[6];
    const float* Wo   = (const float*)d_in[7];
    const float* bori = (const float*)d_in[8];
    float* out = (float*)d_out;

    const int B = in_sizes[0] / (kT * kH);   // 2048
    lstm_ck<<<dim3(B / kNB), dim3(512), 0, stream>>>(x, Wih, Whh, bih, bhh,
                                                     Wp, bpos, Wo, bori, out);
}